// Round 1
// baseline (7547.595 us; speedup 1.0000x reference)
//
#include <hip/hip_runtime.h>
#include <hip/hip_bf16.h>
#include <cmath>

#define FPS_N 8192
#define FPS_K 4096
#define NTHR  1024
#define CS    256

#define NEGINF (-__builtin_inff())

// Minkowski-p3 "sum of |d|^3" with reference-exact f32 op order (no FMA contraction).
__device__ __forceinline__ float p3sum(float x, float y, float z,
                                       float nx, float ny, float nz) {
  float dx = fabsf(__fsub_rn(x, nx));
  float dy = fabsf(__fsub_rn(y, ny));
  float dz = fabsf(__fsub_rn(z, nz));
  float cx = __fmul_rn(__fmul_rn(dx, dx), dx);
  float cy = __fmul_rn(__fmul_rn(dy, dy), dy);
  float cz = __fmul_rn(__fmul_rn(dz, dz), dz);
  return __fadd_rn(__fadd_rn(cx, cy), cz);
}

// Squared Euclidean distance, reference-exact f32 op order.
__device__ __forceinline__ float eucl2(float x, float y, float z,
                                       float nx, float ny, float nz) {
  float dx = __fsub_rn(x, nx);
  float dy = __fsub_rn(y, ny);
  float dz = __fsub_rn(z, nz);
  return __fadd_rn(__fadd_rn(__fmul_rn(dx, dx), __fmul_rn(dy, dy)),
                   __fmul_rn(dz, dz));
}

// ---------------------------------------------------------------------------
// Farthest point sampling: single workgroup, 1024 threads, 8 points/thread.
// Maintains d (=sqrt of min squared distance, bit-exact vs reference) in regs.
// Tie-breaks are lowest-global-index-first at every level (matches jnp.argmax).
// Writes new_node_pos (4096 x 3 f32) in ascending selected-index order.
// ---------------------------------------------------------------------------
__global__ __launch_bounds__(NTHR) void fps_kernel(const float* __restrict__ pos,
                                                   float* __restrict__ pos_out) {
  __shared__ float rv[16];
  __shared__ int   ri[16];
  __shared__ float wposs[3];
  __shared__ int   sc[NTHR];
  const int tid  = threadIdx.x;
  const int lane = tid & 63;
  const int wave = tid >> 6;

  float x[8], y[8], z[8], d2[8], dd[8];
  {
    const float4* p4 = (const float4*)pos + tid * 6;  // 24 floats = 8 points
    float4 q0 = p4[0], q1 = p4[1], q2 = p4[2], q3 = p4[3], q4 = p4[4], q5 = p4[5];
    x[0] = q0.x; y[0] = q0.y; z[0] = q0.z;
    x[1] = q0.w; y[1] = q1.x; z[1] = q1.y;
    x[2] = q1.z; y[2] = q1.w; z[2] = q2.x;
    x[3] = q2.y; y[3] = q2.z; z[3] = q2.w;
    x[4] = q3.x; y[4] = q3.y; z[4] = q3.z;
    x[5] = q3.w; y[5] = q4.x; z[5] = q4.y;
    x[6] = q4.z; y[6] = q4.w; z[6] = q5.x;
    x[7] = q5.y; y[7] = q5.z; z[7] = q5.w;
  }
  const float p0x = pos[0], p0y = pos[1], p0z = pos[2];
#pragma unroll
  for (int j = 0; j < 8; ++j) {
    float s = eucl2(x[j], y[j], z[j], p0x, p0y, p0z);
    d2[j] = s;
    dd[j] = sqrtf(s);
  }
  if (tid == 0) { d2[0] = NEGINF; dd[0] = NEGINF; }

  float bv = 0.f; int bj = 0;   // cached per-thread argmax over my 8 points
  bool chb = true;              // "my local max may have changed"

  for (int k = 0; k < FPS_K - 1; ++k) {
    unsigned long long cb = __ballot(chb ? 1 : 0);
    if (cb != 0ULL) {                 // wave-uniform: recompute wave candidate
      if (chb) {                      // rescan only if my max value changed
        bv = dd[0]; bj = 0;
#pragma unroll
        for (int j = 1; j < 8; ++j)
          if (dd[j] > bv) { bv = dd[j]; bj = j; }  // strict > => lowest j on tie
        chb = false;
      }
      float m = bv;
#pragma unroll
      for (int off = 32; off > 0; off >>= 1)
        m = fmaxf(m, __shfl_xor(m, off));
      unsigned long long eq = __ballot((bv == m) ? 1 : 0);
      int lead = __ffsll(eq) - 1;     // lowest lane holding the max
      int lbj  = __shfl(bj, lead);
      if (lane == 0) {
        rv[wave] = m;
        ri[wave] = ((wave << 6) + lead) * 8 + lbj;
      }
    }
    __syncthreads();  // A: wave candidates visible (stale-but-valid ones persist)

    // final reduce over 16 wave candidates (each 16-lane group redundantly)
    float v  = rv[lane & 15];
    int  idx = ri[lane & 15];
#pragma unroll
    for (int off = 1; off < 16; off <<= 1) {
      float ov = __shfl_xor(v, off);
      int   oi = __shfl_xor(idx, off);
      if (ov > v || (ov == v && oi < idx)) { v = ov; idx = oi; }
    }
    const int fi = idx;  // global winner index (all lanes agree)

    if ((fi >> 3) == tid) {           // owner marks + broadcasts winner coords
      const int jj = fi & 7;
      float sx = x[0], sy = y[0], sz = z[0];
#pragma unroll
      for (int j = 0; j < 8; ++j)
        if (j == jj) { sx = x[j]; sy = y[j]; sz = z[j]; d2[j] = NEGINF; dd[j] = NEGINF; }
      wposs[0] = sx; wposs[1] = sy; wposs[2] = sz;
      chb = true;
    }
    __syncthreads();  // B: winner coords visible

    const float wx = wposs[0], wy = wposs[1], wz = wposs[2];
    unsigned cm = 0;
#pragma unroll
    for (int j = 0; j < 8; ++j) {
      float s = eucl2(x[j], y[j], z[j], wx, wy, wz);
      if (s < d2[j]) { d2[j] = s; cm |= (1u << j); }
    }
    if (cm) {  // sqrt only where the min actually decreased (exec-z skipped wave-wide)
#pragma unroll
      for (int j = 0; j < 8; ++j)
        if (cm & (1u << j)) { dd[j] = sqrtf(d2[j]); if (j == bj) chb = true; }
    }
  }

  // ---- emit selected points in ascending index order (block prefix sum) ----
  int cnt = 0;
#pragma unroll
  for (int j = 0; j < 8; ++j) cnt += (dd[j] == NEGINF) ? 1 : 0;
  sc[tid] = cnt;
  __syncthreads();
  for (int off = 1; off < NTHR; off <<= 1) {
    int vv = (tid >= off) ? sc[tid - off] : 0;
    __syncthreads();
    sc[tid] += vv;
    __syncthreads();
  }
  int base = sc[tid] - cnt;  // exclusive prefix
#pragma unroll
  for (int j = 0; j < 8; ++j) {
    if (dd[j] == NEGINF) {
      pos_out[base * 3 + 0] = x[j];
      pos_out[base * 3 + 1] = y[j];
      pos_out[base * 3 + 2] = z[j];
      ++base;
    }
  }
}

// ---------------------------------------------------------------------------
// W^T (256x256) into scratch (start of mask region; overwritten later).
// ---------------------------------------------------------------------------
__global__ __launch_bounds__(256) void wt_kernel(const float* __restrict__ W,
                                                 float* __restrict__ WT) {
  int i = blockIdx.x * 256 + threadIdx.x;  // 65536 threads
  int c = i >> 8, cp = i & 255;
  WT[i] = W[cp * 256 + c];                 // WT[c][c'] = W[c'][c]
}

// ---------------------------------------------------------------------------
// Fused sparse aggregation + Linear. One block per node m.
// Each of 4 waves scans a disjoint ascending n-range, accumulates member rows
// of h (ballot-compacted, ascending n => deterministic), partials combined in
// fixed wave order, then out[c'] = b[c'] + sum_c agg[c]*WT[c][c'].
// ---------------------------------------------------------------------------
__global__ __launch_bounds__(256) void agg_linear_kernel(
    const float* __restrict__ h, const float* __restrict__ pos,
    const float* __restrict__ nodepos, const float* __restrict__ WT,
    const float* __restrict__ bias, float* __restrict__ embed, float sb) {
  const int m = blockIdx.x;
  const int tid = threadIdx.x;
  const int lane = tid & 63, wave = tid >> 6;
  const float nx = nodepos[m * 3 + 0];
  const float ny = nodepos[m * 3 + 1];
  const float nz = nodepos[m * 3 + 2];
  const float4* h4 = (const float4*)h;

  float4 acc = make_float4(0.f, 0.f, 0.f, 0.f);
  const int base0 = wave * (FPS_N / 4);
  for (int base = base0; base < base0 + (FPS_N / 4); base += 64) {
    int n = base + lane;
    float px = pos[n * 3 + 0], py = pos[n * 3 + 1], pz = pos[n * 3 + 2];
    unsigned long long mb = __ballot((p3sum(px, py, pz, nx, ny, nz) <= sb) ? 1 : 0);
    while (mb) {
      int b = __ffsll(mb) - 1;
      mb &= (mb - 1);
      float4 hv = h4[(size_t)(base + b) * 64 + lane];  // lane owns cols 4l..4l+3
      acc.x += hv.x; acc.y += hv.y; acc.z += hv.z; acc.w += hv.w;
    }
  }

  __shared__ float lacc[4][256];
  lacc[wave][lane * 4 + 0] = acc.x;
  lacc[wave][lane * 4 + 1] = acc.y;
  lacc[wave][lane * 4 + 2] = acc.z;
  lacc[wave][lane * 4 + 3] = acc.w;
  __syncthreads();
  __shared__ float aggrow[256];
  float aggv = ((lacc[0][tid] + lacc[1][tid]) + lacc[2][tid]) + lacc[3][tid];
  aggrow[tid] = aggv;
  __syncthreads();

  float o = bias[tid];
#pragma unroll 8
  for (int c = 0; c < 256; ++c)
    o = fmaf(aggrow[c], WT[c * 256 + tid], o);
  embed[(size_t)m * 256 + tid] = o;
}

// ---------------------------------------------------------------------------
// Mask output: mask[n][m] = (sum|d|^3 <= sb) ? 1.0 : 0.0   (8192 x 4096 f32)
// ---------------------------------------------------------------------------
__global__ __launch_bounds__(256) void mask_kernel(const float* __restrict__ pos,
                                                   const float* __restrict__ nodepos,
                                                   float* __restrict__ maskout,
                                                   float sb) {
  int n  = blockIdx.y;
  int m0 = (blockIdx.x * 256 + threadIdx.x) * 4;
  float x = pos[n * 3 + 0], y = pos[n * 3 + 1], z = pos[n * 3 + 2];
  const float4* np4 = (const float4*)(nodepos + (size_t)m0 * 3);
  float4 a = np4[0], bq = np4[1], cq = np4[2];
  float4 r;
  r.x = (p3sum(x, y, z, a.x,  a.y,  a.z)  <= sb) ? 1.0f : 0.0f;
  r.y = (p3sum(x, y, z, a.w,  bq.x, bq.y) <= sb) ? 1.0f : 0.0f;
  r.z = (p3sum(x, y, z, bq.z, bq.w, cq.x) <= sb) ? 1.0f : 0.0f;
  r.w = (p3sum(x, y, z, cq.y, cq.z, cq.w) <= sb) ? 1.0f : 0.0f;
  *(float4*)(maskout + (size_t)n * FPS_K + m0) = r;
}

extern "C" void kernel_launch(void* const* d_in, const int* in_sizes, int n_in,
                              void* d_out, int out_size, void* d_ws, size_t ws_size,
                              hipStream_t stream) {
  (void)in_sizes; (void)n_in; (void)out_size; (void)d_ws; (void)ws_size;
  const float* h   = (const float*)d_in[0];
  const float* pos = (const float*)d_in[1];
  const float* W   = (const float*)d_in[2];
  const float* b   = (const float*)d_in[3];

  float* out     = (float*)d_out;
  float* embed   = out;                                   // 4096*256
  float* pos_out = out + (size_t)FPS_K * CS;              // 4096*3
  float* mask    = pos_out + (size_t)FPS_K * 3;           // 8192*4096
  float* WT      = mask;  // 256KB scratch inside mask region (overwritten later)

  // Threshold model: ref mask true  <=>  cbrt_f32(s) < 0.3f
  //               <=> s < (0.3f - ulp/2)^3  (correctly-rounded cbrt model)
  const float  t    = 0.3f;
  const float  ulpv = nextafterf(t, 1.0f) - t;
  const double rmid = (double)t - (double)ulpv * 0.5;
  const double C    = rmid * rmid * rmid;
  float sb = (float)C;
  if (!((double)sb < C)) sb = nextafterf(sb, 0.0f);  // largest f32 strictly below C

  hipLaunchKernelGGL(fps_kernel, dim3(1), dim3(NTHR), 0, stream, pos, pos_out);
  hipLaunchKernelGGL(wt_kernel, dim3(256), dim3(256), 0, stream, W, WT);
  hipLaunchKernelGGL(agg_linear_kernel, dim3(FPS_K), dim3(256), 0, stream,
                     h, pos, pos_out, WT, b, embed, sb);
  hipLaunchKernelGGL(mask_kernel, dim3(4, FPS_N), dim3(256), 0, stream,
                     pos, pos_out, mask, sb);
}